// Round 12
// baseline (46.589 us; speedup 1.0000x reference)
//
#include <hip/hip_runtime.h>

// NW kernel regression via MFMA: out = (W @ [V|1]) -> num/den + 1e-6
// W[i,j] = max(0,(2+cos(2*pi*d))*(1-d)/3 + sin(2*pi*d)/(2*pi)), d=|q_i-k_j|/L
//
// Round-12: accumulation moved to the matrix pipe.
//  - wave owns 16 queries; per 32-key tile each lane computes 8 LUT weights
//    (A-frag of mfma_f32_16x16x32_f16), V pre-packed to fp16 B-frag order with
//    ch8 = 1.0 so the denominator is a 9th GEMM column; 1 MFMA/tile replaces
//    18 scalar FMAs/key/wave. K-slot convention is self-consistent (same
//    (lane,j)->key map used for A and B), D-layout = m89-verified
//    col=lane&15,row=4*(lane>>4)+reg.
//  - weight via nearest-neighbor 4096-cell LUT in s=(d/L)^2 (only LDS use)
//  - deterministic partials in d_ws + reduce kernel; prep kernel packs V.

typedef _Float16 h8 __attribute__((ext_vector_type(8)));
typedef float f32x4 __attribute__((ext_vector_type(4)));

#define NCH 8
#define TPB 512        // 8 waves
#define QPB 128        // queries per block = 8 waves x 16
#define KSB 512        // keys per split
#define LUTN 4096

__device__ __forceinline__ float nw_weight_exact(float cd) {
    float r  = __builtin_amdgcn_fractf(cd);
    float sn = __builtin_amdgcn_sinf(r);
    float cs = __builtin_amdgcn_cosf(r);
    float t  = (1.0f - cd) * (1.0f / 3.0f);
    float wt = fmaf(sn, 0.15915494309189535f, fmaf(cs, t, t + t));
    return fmaxf(wt, 0.0f);
}

// pack V (f32 [M,8]) into fp16 B-fragment order:
// vfrag[t*64 + l][j] = Vh[key = t*32 + (l>>4)*8 + j][ch = l&15], ch8=1, ch>8=0
__global__ __launch_bounds__(256) void nw_prep(const float* __restrict__ v,
                                               h8* __restrict__ vfrag, int ntile) {
    const int idx = blockIdx.x * 256 + threadIdx.x;
    if (idx >= ntile * 64) return;
    const int t = idx >> 6, l = idx & 63;
    const int ch = l & 15, g = l >> 4;
    h8 o;
#pragma unroll
    for (int j = 0; j < 8; ++j) {
        const int key = t * 32 + g * 8 + j;
        const float val = (ch < 8) ? v[(size_t)key * 8 + ch]
                                   : (ch == 8 ? 1.0f : 0.0f);
        o[j] = (_Float16)val;
    }
    vfrag[idx] = o;
}

__global__ __launch_bounds__(TPB) void nw_main(const float* __restrict__ q,
                                               const float* __restrict__ k,
                                               const h8* __restrict__ vfrag,
                                               const float* __restrict__ kl,
                                               float* __restrict__ part,
                                               int N) {
    __shared__ float lutw[LUTN + 1];

    const int tid  = threadIdx.x;
    const int lane = tid & 63;
    const int wid  = tid >> 6;

    const float invL = 1.0f / kl[0];
    for (int e = tid; e <= LUTN; e += TPB)
        lutw[e] = nw_weight_exact(__builtin_amdgcn_sqrtf((float)e * (1.0f / (float)LUTN)));
    __syncthreads();

    const int qg = blockIdx.x;
    const int sb = blockIdx.y;
    const int g  = lane >> 4;          // K-group 0..3
    const int qi = qg * QPB + wid * 16 + (lane & 15);   // this lane's A-row query

    const float qx = q[qi * 3 + 0];
    const float qy = q[qi * 3 + 1];
    const float qz = q[qi * 3 + 2];
    const float scale = invL * invL * (float)LUTN;

    f32x4 acc = {0.0f, 0.0f, 0.0f, 0.0f};
    const int t0 = sb * (KSB / 32);

#pragma unroll 2
    for (int t = 0; t < KSB / 32; ++t) {
        const int kt = t0 + t;
        const int kb = kt * 32 + g * 8;            // this lane's 8 keys
        const f32x4* kp4 = (const f32x4*)(k + (size_t)kb * 3);  // 24 floats, 16B-aligned
        float kc[24];
#pragma unroll
        for (int u = 0; u < 6; ++u) *(f32x4*)(kc + 4 * u) = kp4[u];
        const h8 vf = vfrag[(size_t)kt * 64 + lane];

        h8 af;
#pragma unroll
        for (int j = 0; j < 8; ++j) {
            const float dx = qx - kc[3 * j + 0];
            const float dy = qy - kc[3 * j + 1];
            const float dz = qz - kc[3 * j + 2];
            const float d2 = fmaf(dx, dx, fmaf(dy, dy, dz * dz));
            const float fidx = fminf(fmaf(d2, scale, 0.5f), (float)LUTN);
            af[j] = (_Float16)lutw[(int)fidx];     // NN LUT, only LDS op
        }
        acc = __builtin_amdgcn_mfma_f32_16x16x32_f16(af, vf, acc, 0, 0, 0);
    }

    // D: col = lane&15 = channel, row = 4*(lane>>4)+reg = q_local
    const int ch = lane & 15;
    if (ch < 9) {
        const int gi = qg * QPB + wid * 16 + 4 * g;
        *(f32x4*)(part + ((size_t)sb * 10 + ch) * N + gi) = acc;
    }
}

// out[i,c] = (sum_sb num) / (sum_sb den) + 1e-6; coalesced row reads
__global__ __launch_bounds__(256) void nw_reduce(const float* __restrict__ part,
                                                 float* __restrict__ out,
                                                 int N, int nsb) {
    const int i = blockIdx.x * 256 + threadIdx.x;
    if (i >= N) return;
    float o[NCH];
#pragma unroll
    for (int c = 0; c < NCH; ++c) o[c] = 0.0f;
    float den = 0.0f;
    for (int sb = 0; sb < nsb; ++sb) {
        const float* base = part + (size_t)sb * 10 * N + i;
        den += base[8 * (size_t)N];
#pragma unroll
        for (int c = 0; c < NCH; ++c) o[c] += base[(size_t)c * N];
    }
    const float rd = 1.0f / den;
    float4* o4 = (float4*)(out + (size_t)i * NCH);
    o4[0] = make_float4(fmaf(o[0], rd, 1e-6f), fmaf(o[1], rd, 1e-6f),
                        fmaf(o[2], rd, 1e-6f), fmaf(o[3], rd, 1e-6f));
    o4[1] = make_float4(fmaf(o[4], rd, 1e-6f), fmaf(o[5], rd, 1e-6f),
                        fmaf(o[6], rd, 1e-6f), fmaf(o[7], rd, 1e-6f));
}

// generic fallback: one thread per query over all keys (exact math)
__global__ __launch_bounds__(256) void nw_full(const float* __restrict__ q,
                                               const float* __restrict__ k,
                                               const float* __restrict__ v,
                                               const float* __restrict__ kl,
                                               float* __restrict__ out,
                                               int N, int M) {
    const int i = blockIdx.x * 256 + threadIdx.x;
    if (i >= N) return;
    const float qx = q[i * 3 + 0], qy = q[i * 3 + 1], qz = q[i * 3 + 2];
    const float invL = 1.0f / kl[0];
    float num[NCH];
#pragma unroll
    for (int c = 0; c < NCH; ++c) num[c] = 0.0f;
    float den = 0.0f;
    for (int j = 0; j < M; ++j) {
        float dx = qx - k[j * 3 + 0], dy = qy - k[j * 3 + 1], dz = qz - k[j * 3 + 2];
        float d2 = fmaf(dx, dx, fmaf(dy, dy, dz * dz));
        float wt = nw_weight_exact(__builtin_amdgcn_sqrtf(d2) * invL);
        den += wt;
#pragma unroll
        for (int c = 0; c < NCH; ++c) num[c] = fmaf(wt, v[j * NCH + c], num[c]);
    }
    const float rden = 1.0f / den;
#pragma unroll
    for (int c = 0; c < NCH; ++c) out[i * NCH + c] = fmaf(num[c], rden, 1e-6f);
}

extern "C" void kernel_launch(void* const* d_in, const int* in_sizes, int n_in,
                              void* d_out, int out_size, void* d_ws, size_t ws_size,
                              hipStream_t stream) {
    const float* q  = (const float*)d_in[0];
    const float* k  = (const float*)d_in[1];
    const float* v  = (const float*)d_in[2];
    const float* kl = (const float*)d_in[3];
    float* out = (float*)d_out;

    const int N = in_sizes[0] / 3;   // 8192 queries
    const int M = in_sizes[1] / 3;   // 8192 keys

    const int nsb = (M + KSB - 1) / KSB;
    const size_t need_part   = (size_t)nsb * 10 * N * sizeof(float);
    const size_t vfrag_bytes = (size_t)(M / 32) * 64 * sizeof(h8);

    if ((N % QPB) == 0 && (M % KSB) == 0 && ws_size >= need_part + vfrag_bytes) {
        float* part = (float*)d_ws;
        h8* vfrag = (h8*)((char*)d_ws + need_part);
        const int ntile = M / 32;
        nw_prep<<<(ntile * 64 + 255) / 256, 256, 0, stream>>>(v, vfrag, ntile);
        dim3 grid(N / QPB, nsb);
        nw_main<<<grid, TPB, 0, stream>>>(q, k, vfrag, kl, part, N);
        nw_reduce<<<(N + 255) / 256, 256, 0, stream>>>(part, out, N, nsb);
    } else {
        nw_full<<<(N + 255) / 256, 256, 0, stream>>>(q, k, v, kl, out, N, M);
    }
}